// Round 2
// baseline (2202.417 us; speedup 1.0000x reference)
//
#include <hip/hip_runtime.h>
#include <stdint.h>

#define EPS 1e-5f
#define BROWS 64       // output rows per bucket
#define BSHIFT 6       // log2(BROWS)

typedef __attribute__((ext_vector_type(8))) __bf16 bf16x8;
typedef __attribute__((ext_vector_type(8))) unsigned short ushort8;
typedef __attribute__((ext_vector_type(4))) float f32x4;

__device__ __forceinline__ unsigned short f2bf(float f) {
    union { float f; unsigned u; } c; c.f = f;
    unsigned r = c.u + 0x7fffu + ((c.u >> 16) & 1u);   // RNE truncate to bf16
    return (unsigned short)(r >> 16);
}

// ---- pass 1: per-channel sum/sumsq + exact (bucket,tap) histogram -------
// Contiguous per-block streaming (no giant-stride hopping).
__global__ __launch_bounds__(256) void stats_count_kernel(
    const float* __restrict__ f, const int* __restrict__ out_idx,
    const int* __restrict__ off_idx, float* __restrict__ ws,
    int* __restrict__ cnt2, int n)
{
    __shared__ float s_sum[32];
    __shared__ float s_sq[32];
    int tid = threadIdx.x;
    if (tid < 32) { s_sum[tid] = 0.f; s_sq[tid] = 0.f; }
    __syncthreads();
    int c = tid & 31;
    int g = tid >> 5;
    const int per = (n + gridDim.x - 1) / gridDim.x;     // contiguous row chunk
    const int r0 = blockIdx.x * per;
    const int r1 = min(r0 + per, n);
    float sum = 0.f, sq = 0.f;
    for (int r = r0 + g; r < r1; r += 8) {
        float v = f[(size_t)r * 32 + c];
        sum += v; sq += v * v;
    }
    atomicAdd(&s_sum[c], sum);
    atomicAdd(&s_sq[c], sq);
    // exact histogram over (bucket, tap) — fire-and-forget L2 atomics
    for (int i = r0 + tid; i < r1; i += 256)
        atomicAdd(&cnt2[(out_idx[i] >> BSHIFT) * 8 + off_idx[i]], 1);
    __syncthreads();
    if (tid < 32) {
        atomicAdd(&ws[tid],      s_sum[tid]);
        atomicAdd(&ws[32 + tid], s_sq[tid]);
    }
}

// ---- pass 2: BN fold + bf16 weight repack + exclusive scan --------------
__global__ void finalize_scan_kernel(
    const float* __restrict__ gamma, const float* __restrict__ beta,
    const float* __restrict__ weight, float* __restrict__ ws,
    const int* __restrict__ cnt2, int* __restrict__ off2, int* __restrict__ cur2,
    unsigned short* __restrict__ wbf, int n, int nb8)
{
    const int tid = threadIdx.x;
    if (tid < 32) {
        float inv_n = 1.f / (float)n;
        float mean = ws[tid] * inv_n;
        float var  = ws[32 + tid] * inv_n - mean * mean;   // biased var
        float scale = gamma[tid] * rsqrtf(var + EPS);
        ws[64 + tid] = scale;
        ws[96 + tid] = beta[tid] - mean * scale;
    }
    // repack W into bf16 fragment order: idx = ((((t*4+cb)*4+quad)*16)+m)*8+j
    // holds W[t][quad*8+j][cb*16+m]
    for (int idx = tid; idx < 16384; idx += blockDim.x) {
        int j  = idx & 7;
        int mm = (idx >> 3) & 15;
        int qd = (idx >> 7) & 3;
        int cb = (idx >> 9) & 3;
        int t  = idx >> 11;
        wbf[idx] = f2bf(weight[((size_t)t * 32 + qd * 8 + j) * 64 + cb * 16 + mm]);
    }
    // exclusive scan of cnt2[nb8] -> off2 (+ total at off2[nb8]), cur2 = off2
    __shared__ int partial[1024];
    const int bdim = blockDim.x;
    const int per = (nb8 + bdim - 1) / bdim;
    const int lo = tid * per;
    const int hi = min(lo + per, nb8);
    int s = 0;
    for (int i = lo; i < hi; ++i) s += cnt2[i];
    partial[tid] = s;
    __syncthreads();
    if (tid == 0) {
        int acc = 0;
        for (int i = 0; i < bdim; ++i) { int t2 = partial[i]; partial[i] = acc; acc += t2; }
        off2[nb8] = acc;
    }
    __syncthreads();
    int acc = partial[tid];
    for (int i = lo; i < hi; ++i) { off2[i] = acc; cur2[i] = acc; acc += cnt2[i]; }
}

// ---- pass 3: BN+ReLU+bf16 convert, place payload into bucket slots ------
// Reads feat coalesced (contiguous per block); the only random memory op is
// a fire-and-forget 16B payload store + 4B meta store (no random reads).
__global__ __launch_bounds__(256) void pay_kernel(
    const float* __restrict__ feat, const int* __restrict__ out_idx,
    const int* __restrict__ off_idx, const float* __restrict__ ws,
    int* __restrict__ cur2, int* __restrict__ meta,
    unsigned short* __restrict__ pay, int n)
{
    const int lane = threadIdx.x & 63;
    const int m    = lane & 15;
    const int quad = lane >> 4;
    const int wid  = threadIdx.x >> 6;

    float scl[8], sft[8];
    #pragma unroll
    for (int j = 0; j < 8; ++j) {
        int k = quad * 8 + j;
        scl[j] = ws[64 + k];
        sft[j] = ws[96 + k];
    }

    const int ntiles = (n + 15) >> 4;
    const int tpb = (ntiles + gridDim.x - 1) / gridDim.x;   // contiguous tiles/block
    const int t0 = blockIdx.x * tpb;
    const int t1 = min(t0 + tpb, ntiles);

    for (int tile = t0 + wid; tile < t1; tile += 4) {
        const int p  = (tile << 4) + m;
        const int pc = p < n ? p : n - 1;

        const f32x4* fp = (const f32x4*)(feat + (size_t)pc * 32 + quad * 8);
        f32x4 x0 = fp[0];
        f32x4 x1 = fp[1];

        ushort8 af;
        #pragma unroll
        for (int j = 0; j < 4; ++j)
            af[j] = f2bf(fmaxf(x0[j] * scl[j] + sft[j], 0.f));
        #pragma unroll
        for (int j = 0; j < 4; ++j)
            af[4 + j] = f2bf(fmaxf(x1[j] * scl[4 + j] + sft[4 + j], 0.f));

        int slot = 0;
        if (quad == 0 && p < n) {
            int oi = out_idx[p];
            int tp = off_idx[p];
            slot = atomicAdd(&cur2[(oi >> BSHIFT) * 8 + tp], 1);
            meta[slot] = (oi & (BROWS - 1)) | (tp << BSHIFT);
        }
        slot = __shfl(slot, m, 64);     // broadcast from quad0 lane m
        if (p < n)
            *(ushort8*)(pay + (size_t)slot * 32 + quad * 8) = af;
    }
}

// ---- pass 4: contiguous payload read + tap-skipped MFMA + dense store ---
// One block per 64-row bucket. All reads contiguous; W fragments from LDS;
// zero global atomics; every out row written exactly once (clears poison).
__global__ __launch_bounds__(256, 2) void gather_kernel(
    const int* __restrict__ off2, const int* __restrict__ meta,
    const unsigned short* __restrict__ pay, const unsigned short* __restrict__ wbf,
    float* __restrict__ out, int n)
{
    __shared__ __align__(16) float s_acc[BROWS][64];   // 16 KB
    __shared__ f32x4 s_w4[2048];                       // 32 KB bf16 W fragments
    const int lane = threadIdx.x & 63;
    const int m    = lane & 15;
    const int quad = lane >> 4;
    const int wid  = threadIdx.x >> 6;
    const int b    = blockIdx.x;

    // stage W + zero accumulator
    {
        const f32x4* src = (const f32x4*)wbf;
        for (int i = threadIdx.x; i < 2048; i += blockDim.x) s_w4[i] = src[i];
        f32x4* pz = (f32x4*)&s_acc[0][0];
        for (int i = threadIdx.x; i < BROWS * 64 / 4; i += blockDim.x)
            pz[i] = (f32x4){0.f, 0.f, 0.f, 0.f};
    }
    const int start = off2[b * 8];
    const int end   = off2[b * 8 + 8];
    __syncthreads();

    const unsigned short* sw = (const unsigned short*)s_w4;
    const ushort8 zz = {0, 0, 0, 0, 0, 0, 0, 0};
    const int k = end - start;
    const int nch = (k + 15) >> 4;

    for (int c = wid; c < nch; c += 4) {
        const int sl = start + c * 16 + m;
        const bool valid = sl < end;
        int row = -1, tap = -1;
        if (valid) {
            int mv = meta[sl];
            row = mv & (BROWS - 1);
            tap = mv >> BSHIFT;
        }
        const ushort8 af = *(const ushort8*)(pay + (size_t)(valid ? sl : 0) * 32 + quad * 8);

        f32x4 acc[4];
        #pragma unroll
        for (int cb = 0; cb < 4; ++cb) acc[cb] = (f32x4){0.f, 0.f, 0.f, 0.f};

        // slots are tap-sorted within the bucket -> ~1-2 live taps per chunk
        #pragma unroll
        for (int t = 0; t < 8; ++t) {
            if (__any(tap == t)) {
                ushort8 am = (tap == t) ? af : zz;
                bf16x8 a = __builtin_bit_cast(bf16x8, am);
                #pragma unroll
                for (int cb = 0; cb < 4; ++cb) {
                    const ushort8 bw = *(const ushort8*)(&sw[((((t * 4 + cb) * 4 + quad) * 16) + m) * 8]);
                    acc[cb] = __builtin_amdgcn_mfma_f32_16x16x32_bf16(
                        a, __builtin_bit_cast(bf16x8, bw), acc[cb], 0, 0, 0);
                }
            }
        }
        // D row = quad*4+i (point slot), col = cb*16+m (channel)
        #pragma unroll
        for (int i = 0; i < 4; ++i) {
            int r = __shfl(row, quad * 4 + i, 64);
            if (r >= 0) {
                #pragma unroll
                for (int cb = 0; cb < 4; ++cb)
                    atomicAdd(&s_acc[r][cb * 16 + m], acc[cb][i]);
            }
        }
    }
    __syncthreads();

    const int base_row = b << BSHIFT;
    const int rows = min(BROWS, n - base_row);
    for (int idx = threadIdx.x; idx < rows * 16; idx += blockDim.x) {
        int r = idx >> 4, c4 = idx & 15;
        ((f32x4*)(out + (size_t)(base_row + r) * 64))[c4] = ((const f32x4*)&s_acc[r][0])[c4];
    }
}

// ======================= legacy fallback path ============================
__global__ void finalize_kernel(const float* __restrict__ gamma, const float* __restrict__ beta,
                                float* __restrict__ ws, int n) {
    int c = threadIdx.x;
    if (c < 32) {
        float inv_n = 1.f / (float)n;
        float mean = ws[c] * inv_n;
        float var  = ws[32 + c] * inv_n - mean * mean;
        float scale = gamma[c] * rsqrtf(var + EPS);
        ws[64 + c] = scale;
        ws[96 + c] = beta[c] - mean * scale;
    }
}

__global__ __launch_bounds__(256, 2) void spconv_kernel(
    const float* __restrict__ feat, const float* __restrict__ weight,
    const int* __restrict__ out_idx, const int* __restrict__ off_idx,
    const float* __restrict__ ws, float* __restrict__ out, int n)
{
    const int lane = threadIdx.x & 63;
    const int m    = lane & 15;
    const int quad = lane >> 4;
    const int wave   = blockIdx.x * (blockDim.x >> 6) + (threadIdx.x >> 6);
    const int nwaves = gridDim.x * (blockDim.x >> 6);

    float scl[8], sft[8];
    #pragma unroll
    for (int j = 0; j < 8; ++j) {
        int k = quad * 8 + j;
        scl[j] = ws[64 + k];
        sft[j] = ws[96 + k];
    }

    ushort8 wf[8][4];
    #pragma unroll
    for (int t = 0; t < 8; ++t) {
        #pragma unroll
        for (int cb = 0; cb < 4; ++cb) {
            ushort8 v;
            #pragma unroll
            for (int j = 0; j < 8; ++j) {
                int k = quad * 8 + j;
                v[j] = f2bf(weight[((size_t)t * 32 + k) * 64 + cb * 16 + m]);
            }
            wf[t][cb] = v;
        }
    }

    const ushort8 zz = {0, 0, 0, 0, 0, 0, 0, 0};
    const int ntiles = (n + 15) >> 4;

    for (int tile = wave; tile < ntiles; tile += nwaves) {
        const int p_base = tile << 4;
        const int p  = p_base + m;
        const int pc = p < n ? p : n - 1;

        const f32x4* fp = (const f32x4*)(feat + (size_t)pc * 32 + quad * 8);
        f32x4 x0 = fp[0];
        f32x4 x1 = fp[1];

        ushort8 af;
        #pragma unroll
        for (int j = 0; j < 4; ++j)
            af[j] = f2bf(fmaxf(x0[j] * scl[j] + sft[j], 0.f));
        #pragma unroll
        for (int j = 0; j < 4; ++j)
            af[4 + j] = f2bf(fmaxf(x1[j] * scl[4 + j] + sft[4 + j], 0.f));

        const int tap = (p < n) ? off_idx[p] : -1;

        f32x4 acc[4];
        #pragma unroll
        for (int cb = 0; cb < 4; ++cb) acc[cb] = (f32x4){0.f, 0.f, 0.f, 0.f};

        #pragma unroll
        for (int t = 0; t < 8; ++t) {
            ushort8 am = (tap == t) ? af : zz;
            bf16x8 a = __builtin_bit_cast(bf16x8, am);
            #pragma unroll
            for (int cb = 0; cb < 4; ++cb) {
                acc[cb] = __builtin_amdgcn_mfma_f32_16x16x32_bf16(
                    a, __builtin_bit_cast(bf16x8, wf[t][cb]), acc[cb], 0, 0, 0);
            }
        }

        int o[4]; bool ok[4];
        #pragma unroll
        for (int i = 0; i < 4; ++i) {
            int pr = p_base + quad * 4 + i;
            ok[i] = pr < n;
            o[i]  = ok[i] ? out_idx[pr] : 0;
        }
        #pragma unroll
        for (int cb = 0; cb < 4; ++cb) {
            #pragma unroll
            for (int i = 0; i < 4; ++i) {
                if (ok[i])
                    atomicAdd(out + (size_t)o[i] * 64 + cb * 16 + m, acc[cb][i]);
            }
        }
    }
}

extern "C" void kernel_launch(void* const* d_in, const int* in_sizes, int n_in,
                              void* d_out, int out_size, void* d_ws, size_t ws_size,
                              hipStream_t stream) {
    const float* features  = (const float*)d_in[0];
    const float* gamma     = (const float*)d_in[1];
    const float* beta      = (const float*)d_in[2];
    const float* weight    = (const float*)d_in[3];
    const int*   out_index = (const int*)d_in[4];
    const int*   off_index = (const int*)d_in[5];
    float* out = (float*)d_out;
    float* ws  = (float*)d_ws;
    const int n = in_sizes[0] / 32;

    const int nb  = (n + BROWS - 1) >> BSHIFT;
    const int nb8 = nb * 8;

    // ws layout in 4-byte units:
    // [0,64) sums+sumsq | [64,128) scale+shift | cnt2[nb8] | off2[nb8+1] |
    // cur2[nb8] | wbf (8192 ints = 32KB bf16) | meta[n] | pay (n*16 ints)
    size_t o_cnt = 128;
    size_t o_off = o_cnt + (size_t)nb8;
    size_t o_cur = o_off + (size_t)nb8 + 1;
    size_t o_wbf = (o_cur + (size_t)nb8 + 3) & ~(size_t)3;
    size_t o_meta = o_wbf + 8192;
    size_t o_pay = (o_meta + (size_t)n + 3) & ~(size_t)3;
    size_t need  = (o_pay + (size_t)n * 16) * 4;

    if (ws_size >= need) {
        int* cnt2 = (int*)ws + o_cnt;
        int* off2 = (int*)ws + o_off;
        int* cur2 = (int*)ws + o_cur;
        unsigned short* wbf = (unsigned short*)((int*)ws + o_wbf);
        int* meta = (int*)ws + o_meta;
        unsigned short* pay = (unsigned short*)((int*)ws + o_pay);

        // zero BN sums + histogram (~1 MB); everything else fully overwritten
        hipMemsetAsync(d_ws, 0, (o_cnt + (size_t)nb8) * sizeof(int), stream);
        stats_count_kernel<<<2048, 256, 0, stream>>>(features, out_index, off_index,
                                                     ws, cnt2, n);
        finalize_scan_kernel<<<1, 1024, 0, stream>>>(gamma, beta, weight, ws,
                                                     cnt2, off2, cur2, wbf, n, nb8);
        pay_kernel<<<2048, 256, 0, stream>>>(features, out_index, off_index, ws,
                                             cur2, meta, pay, n);
        gather_kernel<<<nb, 256, 0, stream>>>(off2, meta, pay, wbf, out, n);
    } else {
        // fallback: legacy direct-atomic path
        hipMemsetAsync(d_out, 0, (size_t)out_size * sizeof(float), stream);
        hipMemsetAsync(d_ws, 0, 64 * sizeof(float), stream);
        stats_count_kernel<<<2048, 256, 0, stream>>>(features, out_index, off_index,
                                                     ws, (int*)ws + 64, n); // cnt unused sink
        finalize_kernel<<<1, 64, 0, stream>>>(gamma, beta, ws, n);
        spconv_kernel<<<1024, 256, 0, stream>>>(features, weight, out_index, off_index,
                                                ws, out, n);
    }
}